// Round 1
// baseline (207.955 us; speedup 1.0000x reference)
//
#include <hip/hip_runtime.h>

// Problem constants
#define NN 32
#define DD 128
#define SS 128
#define MM 64
#define PP 4096              // MM*MM
#define DSZ (DD * SS)        // 16384

// Workspace layout (float offsets)
#define OFF_CPK 0                          // 5 packed coeff planes [5][D][S]
#define OFF_MC  (OFF_CPK + 5 * DSZ)        // column means  [N][D][M]
#define OFF_DG  (OFF_MC + NN * DD * MM)    // diagonals     [N][D][M]
#define OFF_MD  (OFF_DG + NN * DD * MM)    // mean(diag)    [N][D]
#define OFF_MA  (OFF_MD + NN * DD)         // mean(all)     [N][D]
#define OFF_UT  (OFF_MA + NN * DD)         // u transposed  [N][M][S]
#define OFF_V   (OFF_UT + NN * MM * SS)    // v             [N][S]

// ---------------------------------------------------------------------------
// Kernel 0: unpack coeffs [D,S,5] (AoS) -> 5 contiguous planes [5][D][S]
// ---------------------------------------------------------------------------
__global__ __launch_bounds__(256) void pack_coeffs_k(const float* __restrict__ coeffs,
                                                     float* __restrict__ cpk) {
    int idx = blockIdx.x * 256 + threadIdx.x;   // idx = d*S + s
    if (idx < DSZ) {
#pragma unroll
        for (int b = 0; b < 5; ++b)
            cpk[b * DSZ + idx] = coeffs[idx * 5 + b];
    }
}

// ---------------------------------------------------------------------------
// Kernel 1: per-(n,d) stats. One wave (64 threads) per 64x64 matrix.
// Thread t: iq = t>>4 (row group), jq = t&15 (4 columns via float4).
// ---------------------------------------------------------------------------
__global__ __launch_bounds__(64) void stats_k(const float* __restrict__ x,
                                              float* __restrict__ mc,
                                              float* __restrict__ dg,
                                              float* __restrict__ md,
                                              float* __restrict__ ma) {
    int nd = blockIdx.x;                       // n*D + d
    const float* base = x + (size_t)nd * PP;
    int t  = threadIdx.x;
    int iq = t >> 4;
    int jq = t & 15;

    float4 cs = make_float4(0.f, 0.f, 0.f, 0.f);
#pragma unroll
    for (int r = 0; r < 16; ++r) {
        int i = r * 4 + iq;
        float4 v = *(const float4*)(base + i * MM + jq * 4);
        cs.x += v.x; cs.y += v.y; cs.z += v.z; cs.w += v.w;
    }
    // reduce across the 4 iq groups (lane bits 4,5)
#pragma unroll
    for (int m = 16; m <= 32; m <<= 1) {
        cs.x += __shfl_xor(cs.x, m);
        cs.y += __shfl_xor(cs.y, m);
        cs.z += __shfl_xor(cs.z, m);
        cs.w += __shfl_xor(cs.w, m);
    }
    if (iq == 0) {
        float4 o = make_float4(cs.x * (1.f / 64.f), cs.y * (1.f / 64.f),
                               cs.z * (1.f / 64.f), cs.w * (1.f / 64.f));
        *(float4*)(mc + nd * MM + jq * 4) = o;
    }
    // diagonal (lane t holds x[t][t]); lines already hot in L1 from the sweep
    float dv = base[t * 65];
    dg[nd * MM + t] = dv;
    float dsum = dv;
#pragma unroll
    for (int m = 1; m <= 32; m <<= 1) dsum += __shfl_xor(dsum, m);
    // grand total: sum each lane's 4-column sum across the 16 jq (lane bits 0-3)
    float tot = cs.x + cs.y + cs.z + cs.w;
#pragma unroll
    for (int m = 1; m <= 8; m <<= 1) tot += __shfl_xor(tot, m);
    if (t == 0) {
        md[nd] = dsum * (1.f / 64.f);
        ma[nd] = tot * (1.f / 4096.f);
    }
}

// ---------------------------------------------------------------------------
// Kernel 1b: u[n,s,i] = 0.5 * sum_d (c0[d,s]*mc[n,d,i] + c2[d,s]*dg[n,d,i])
//            stored transposed: ut[n][i][s]  (so GEMM epilogue loads vectorize)
//            v[n,s]  = sum_d (c3*md + c4*ma) + bias[s]   (blocks with ig==0)
// Grid (16, N), block 256: s = t&127 (coalesced coeff reads), 2 i's per thread.
// ---------------------------------------------------------------------------
__global__ __launch_bounds__(256) void combine_k(const float* __restrict__ cpk,
                                                 const float* __restrict__ mc,
                                                 const float* __restrict__ dg,
                                                 const float* __restrict__ md,
                                                 const float* __restrict__ ma,
                                                 const float* __restrict__ bias,
                                                 float* __restrict__ ut,
                                                 float* __restrict__ vv) {
    int ig = blockIdx.x;          // 0..15 -> i group of 4
    int n  = blockIdx.y;
    int t  = threadIdx.x;
    int s  = t & 127;
    int ih = t >> 7;              // 0/1, wave-uniform
    int i0 = ig * 4 + ih * 2;

    const float* c0p = cpk + 0 * DSZ + s;
    const float* c2p = cpk + 2 * DSZ + s;
    const float* c3p = cpk + 3 * DSZ + s;
    const float* c4p = cpk + 4 * DSZ + s;

    float u0 = 0.f, u1 = 0.f, va = 0.f;
    const bool dov = (ig == 0 && ih == 0);
#pragma unroll 4
    for (int d = 0; d < DD; ++d) {
        float c0 = c0p[d * SS];
        float c2 = c2p[d * SS];
        int bidx = (n * DD + d) * MM + i0;
        float m0 = mc[bidx], m1 = mc[bidx + 1];
        float g0 = dg[bidx], g1 = dg[bidx + 1];
        u0 += c0 * m0 + c2 * g0;
        u1 += c0 * m1 + c2 * g1;
        if (dov)
            va += c3p[d * SS] * md[n * DD + d] + c4p[d * SS] * ma[n * DD + d];
    }
    ut[(n * MM + i0) * SS + s]       = 0.5f * u0;
    ut[(n * MM + i0 + 1) * SS + s]   = 0.5f * u1;
    if (dov) vv[n * SS + s] = va + bias[s];
}

// ---------------------------------------------------------------------------
// Kernel 2: out[n,s,p] = sum_d c1[d,s]*x[n,d,p] + ut[n,i,s] + ut[n,j,s] + v[n,s]
// Tile: 128 s x 128 p per block, 256 threads, 8x8 accum/thread,
// double-buffered LDS over K (BK=8), one barrier per K-chunk.
// ---------------------------------------------------------------------------
#define TPK 128
#define BK  8
__global__ __launch_bounds__(256) void gemm_k(const float* __restrict__ x,
                                              const float* __restrict__ cpk1,
                                              const float* __restrict__ ut,
                                              const float* __restrict__ vv,
                                              float* __restrict__ out) {
    __shared__ float xs[2][BK][TPK];
    __shared__ float cls[2][BK][SS];

    int pt = blockIdx.x;
    int n  = blockIdx.y;
    int p0 = pt * TPK;
    int t  = threadIdx.x;
    int tx = t & 15, ty = t >> 4;
    int px = tx * 8, sy = ty * 8;
    int kr = t >> 5, pc = (t & 31) * 4;        // loader: row kr (0..7), 4 floats

    const float* xbase = x + (size_t)n * DD * PP + p0;

    float4 xv = *(const float4*)(xbase + kr * PP + pc);
    float4 cv = *(const float4*)(cpk1 + kr * SS + pc);
    *(float4*)&xs[0][kr][pc]  = xv;
    *(float4*)&cls[0][kr][pc] = cv;
    __syncthreads();

    float acc[8][8];
#pragma unroll
    for (int a = 0; a < 8; ++a)
#pragma unroll
        for (int b = 0; b < 8; ++b) acc[a][b] = 0.f;

    int buf = 0;
    for (int k0 = 0; k0 < DD / BK; ++k0) {
        if (k0 < DD / BK - 1) {
            xv = *(const float4*)(xbase + (size_t)((k0 + 1) * BK + kr) * PP + pc);
            cv = *(const float4*)(cpk1 + ((k0 + 1) * BK + kr) * SS + pc);
        }
#pragma unroll
        for (int kk = 0; kk < BK; ++kk) {
            float xr[8], cr[8];
            *(float4*)&xr[0] = *(const float4*)&xs[buf][kk][px];
            *(float4*)&xr[4] = *(const float4*)&xs[buf][kk][px + 4];
            *(float4*)&cr[0] = *(const float4*)&cls[buf][kk][sy];
            *(float4*)&cr[4] = *(const float4*)&cls[buf][kk][sy + 4];
#pragma unroll
            for (int ss = 0; ss < 8; ++ss)
#pragma unroll
                for (int pp = 0; pp < 8; ++pp)
                    acc[ss][pp] += cr[ss] * xr[pp];
        }
        if (k0 < DD / BK - 1) {
            // safe: everyone passed the barrier of the previous iter, so buf^1's
            // readers are done; write it, then one barrier before reading it.
            *(float4*)&xs[buf ^ 1][kr][pc]  = xv;
            *(float4*)&cls[buf ^ 1][kr][pc] = cv;
            __syncthreads();
            buf ^= 1;
        }
    }

    // epilogue: p = p0+px+pp -> i fixed per thread, j = j0+pp
    int i  = (p0 + px) >> 6;
    int j0 = (p0 + px) & 63;

    float ui[8], vb[8];
    *(float4*)&ui[0] = *(const float4*)(ut + (n * MM + i) * SS + sy);
    *(float4*)&ui[4] = *(const float4*)(ut + (n * MM + i) * SS + sy + 4);
    *(float4*)&vb[0] = *(const float4*)(vv + n * SS + sy);
    *(float4*)&vb[4] = *(const float4*)(vv + n * SS + sy + 4);

#pragma unroll
    for (int pp = 0; pp < 8; ++pp) {
        float ujv[8];
        *(float4*)&ujv[0] = *(const float4*)(ut + (n * MM + j0 + pp) * SS + sy);
        *(float4*)&ujv[4] = *(const float4*)(ut + (n * MM + j0 + pp) * SS + sy + 4);
#pragma unroll
        for (int ss = 0; ss < 8; ++ss) acc[ss][pp] += ujv[ss];
    }

#pragma unroll
    for (int ss = 0; ss < 8; ++ss) {
        float o[8];
#pragma unroll
        for (int pp = 0; pp < 8; ++pp) o[pp] = acc[ss][pp] + ui[ss] + vb[ss];
        float* op = out + ((size_t)(n * SS + sy + ss)) * PP + p0 + px;
        *(float4*)(op)     = *(float4*)&o[0];
        *(float4*)(op + 4) = *(float4*)&o[4];
    }
}

// ---------------------------------------------------------------------------
extern "C" void kernel_launch(void* const* d_in, const int* in_sizes, int n_in,
                              void* d_out, int out_size, void* d_ws, size_t ws_size,
                              hipStream_t stream) {
    const float* x      = (const float*)d_in[0];   // [N,D,M,M]
    const float* coeffs = (const float*)d_in[1];   // [D,S,5]
    const float* bias   = (const float*)d_in[2];   // [S]
    float* out = (float*)d_out;
    float* ws  = (float*)d_ws;

    float* cpk = ws + OFF_CPK;
    float* mc  = ws + OFF_MC;
    float* dg  = ws + OFF_DG;
    float* md  = ws + OFF_MD;
    float* ma  = ws + OFF_MA;
    float* ut  = ws + OFF_UT;
    float* vv  = ws + OFF_V;

    pack_coeffs_k<<<(DSZ + 255) / 256, 256, 0, stream>>>(coeffs, cpk);
    stats_k<<<NN * DD, 64, 0, stream>>>(x, mc, dg, md, ma);
    combine_k<<<dim3(16, NN), 256, 0, stream>>>(cpk, mc, dg, md, ma, bias, ut, vv);
    gemm_k<<<dim3(PP / TPK, NN), 256, 0, stream>>>(x, cpk + 1 * DSZ, ut, vv, out);
}

// Round 2
// 171.176 us; speedup vs baseline: 1.2149x; 1.2149x over previous
//
#include <hip/hip_runtime.h>

#define NN 32
#define DD 128
#define SS 128
#define MM 64
#define PP 4096              // MM*MM
#define DSZ (DD * SS)

typedef short bf16x8 __attribute__((ext_vector_type(8)));
typedef float f32x4  __attribute__((ext_vector_type(4)));

// Workspace layout (float offsets)
#define OFF_CPK 0                          // fp32 planes [5][D][S] (plane 1 unused)
#define OFF_C1T (OFF_CPK + 5 * DSZ)        // c1 transposed bf16 [S][D] (DSZ ushorts)
#define OFF_MC  (OFF_C1T + DSZ / 2)        // column means [N][D][M]
#define OFF_DG  (OFF_MC + NN * DD * MM)    // diagonals    [N][D][M]
#define OFF_MD  (OFF_DG + NN * DD * MM)    // mean(diag)   [N][D]
#define OFF_MA  (OFF_MD + NN * DD)         // mean(all)    [N][D]
#define OFF_UP  (OFF_MA + NN * DD)         // u' [N][S][M]  (0.5*w + 0.5*v, bias folded)

__device__ __forceinline__ unsigned int fbits(float f) {
    union { float f; unsigned int u; } c; c.f = f; return c.u;
}

// ---------------------------------------------------------------------------
// Kernel 0: coeffs [D,S,5] AoS -> fp32 planes [b][D][S] (b=0,2,3,4) and
//           c1t bf16 [S][D] (RNE) for the MFMA A-operand.
// ---------------------------------------------------------------------------
__global__ __launch_bounds__(256) void pack_k(const float* __restrict__ coeffs,
                                              float* __restrict__ cpk,
                                              unsigned short* __restrict__ c1t) {
    int g = blockIdx.x * 256 + threadIdx.x;   // g = d*S + s
    int d = g >> 7, s = g & 127;
    float v0 = coeffs[g * 5 + 0];
    float v1 = coeffs[g * 5 + 1];
    float v2 = coeffs[g * 5 + 2];
    float v3 = coeffs[g * 5 + 3];
    float v4 = coeffs[g * 5 + 4];
    cpk[0 * DSZ + g] = v0;
    cpk[2 * DSZ + g] = v2;
    cpk[3 * DSZ + g] = v3;
    cpk[4 * DSZ + g] = v4;
    unsigned int u = fbits(v1);
    u += 0x7fffu + ((u >> 16) & 1);           // round to nearest even
    c1t[s * DD + d] = (unsigned short)(u >> 16);
}

// ---------------------------------------------------------------------------
// Kernel 1: per-(n,d) stats; 4 waves/block, one 64x64 matrix per wave.
// Diagonal extracted during the main sweep (no second global pass).
// ---------------------------------------------------------------------------
__global__ __launch_bounds__(256) void stats_k(const float* __restrict__ x,
                                               float* __restrict__ mc,
                                               float* __restrict__ dg,
                                               float* __restrict__ md,
                                               float* __restrict__ ma) {
    int nd = blockIdx.x * 4 + (threadIdx.x >> 6);
    int l  = threadIdx.x & 63;
    const float* base = x + (size_t)nd * PP;
    int iq = l >> 4, jq = l & 15;

    float4 cs = make_float4(0.f, 0.f, 0.f, 0.f);
    float dv = 0.f;
#pragma unroll
    for (int r = 0; r < 16; ++r) {
        float4 v = *(const float4*)(base + (r * 4 + iq) * MM + jq * 4);
        cs.x += v.x; cs.y += v.y; cs.z += v.z; cs.w += v.w;
        if (r == jq)   // this lane's tile contains diag element i = 4*jq + iq
            dv = (iq == 0) ? v.x : (iq == 1) ? v.y : (iq == 2) ? v.z : v.w;
    }
#pragma unroll
    for (int m = 16; m <= 32; m <<= 1) {
        cs.x += __shfl_xor(cs.x, m);
        cs.y += __shfl_xor(cs.y, m);
        cs.z += __shfl_xor(cs.z, m);
        cs.w += __shfl_xor(cs.w, m);
    }
    if (iq == 0) {
        float4 o = make_float4(cs.x * (1.f / 64.f), cs.y * (1.f / 64.f),
                               cs.z * (1.f / 64.f), cs.w * (1.f / 64.f));
        *(float4*)(mc + nd * MM + jq * 4) = o;
    }
    dg[nd * MM + 4 * jq + iq] = dv;
    float dsum = dv;
#pragma unroll
    for (int m = 1; m <= 32; m <<= 1) dsum += __shfl_xor(dsum, m);
    float tot = cs.x + cs.y + cs.z + cs.w;
#pragma unroll
    for (int m = 1; m <= 8; m <<= 1) tot += __shfl_xor(tot, m);
    if (l == 0) {
        md[nd] = dsum * (1.f / 64.f);
        ma[nd] = tot * (1.f / 4096.f);
    }
}

// ---------------------------------------------------------------------------
// Kernel 1b: u'[n][s][i] = 0.5*( sum_d c0*mc + c2*dg  +  sum_d c3*md + c4*ma + bias[s] )
// epilogue then does out += u'[s][i] + u'[s][j] (v+bias counted exactly once).
// grid (8 sg, N), block 256: i = t&63 (coalesced), 4 s per thread.
// ---------------------------------------------------------------------------
__global__ __launch_bounds__(256) void combine_k(const float* __restrict__ cpk,
                                                 const float* __restrict__ mc,
                                                 const float* __restrict__ dg,
                                                 const float* __restrict__ md,
                                                 const float* __restrict__ ma,
                                                 const float* __restrict__ bias,
                                                 float* __restrict__ up) {
    int sg = blockIdx.x, n = blockIdx.y;
    int t  = threadIdx.x;
    int i  = t & 63;
    int sq = t >> 6;                 // 0..3 (wave-uniform)
    int s0 = sg * 16 + sq * 4;

    const float* c0p = cpk + 0 * DSZ;
    const float* c2p = cpk + 2 * DSZ;
    const float* c3p = cpk + 3 * DSZ;
    const float* c4p = cpk + 4 * DSZ;

    float wacc[4] = {0.f, 0.f, 0.f, 0.f};
    float vacc[4] = {0.f, 0.f, 0.f, 0.f};
#pragma unroll 2
    for (int d = 0; d < DD; ++d) {
        int bidx = (n * DD + d) * MM + i;
        float m  = mc[bidx];
        float g  = dg[bidx];
        float mdv = md[n * DD + d];
        float mav = ma[n * DD + d];
#pragma unroll
        for (int r = 0; r < 4; ++r) {
            int cs = d * SS + s0 + r;
            wacc[r] += c0p[cs] * m + c2p[cs] * g;
            vacc[r] += c3p[cs] * mdv + c4p[cs] * mav;
        }
    }
#pragma unroll
    for (int r = 0; r < 4; ++r) {
        int s = s0 + r;
        up[((size_t)n * SS + s) * MM + i] = 0.5f * (wacc[r] + vacc[r] + bias[s]);
    }
}

// ---------------------------------------------------------------------------
// Kernel 2: MFMA GEMM. out[n,s,p] = sum_d c1[d,s]*x[n,d,p] + u'[s,i] + u'[s,j]
// Block: (p-tile 128, n). 4 waves: wave covers 64s x 64p. 16x16x32 bf16 MFMA.
// A-frags from global c1t[S][D] (16B contiguous). B-frags from global x as
// 8 strided dwords (full-cache-line segments), truncate-packed to bf16.
// No LDS in the K-loop; one barrier total (u' stage for epilogue).
// ---------------------------------------------------------------------------
#define USTR 68   // LDS stride for u' tile [128][64] (+4 pad: aligned + conflict-free)
__global__ __launch_bounds__(256, 3) void gemm_k(const float* __restrict__ x,
                                                 const unsigned short* __restrict__ c1t,
                                                 const float* __restrict__ up,
                                                 float* __restrict__ out) {
    __shared__ float us[SS * USTR];

    int n  = blockIdx.y;
    int p0 = blockIdx.x * 128;
    int t  = threadIdx.x;
    int w  = t >> 6, l = t & 63;
    int wp = w & 1, wsn = w >> 1;
    int q  = l >> 4, c = l & 15;

    // stage u'[n] (128 s x 64 i fp32) into LDS
    const float* upn = up + (size_t)n * SS * MM;
#pragma unroll
    for (int e = t; e < SS * MM / 4; e += 256) {
        int s  = e >> 4;
        int i4 = (e & 15) * 4;
        *(f32x4*)&us[s * USTR + i4] = *(const f32x4*)(upn + s * MM + i4);
    }
    __syncthreads();

    int p0w = p0 + wp * 64;            // this wave's p base (64-aligned)
    int s0w = wsn * 64;                // this wave's s base
    int iw  = p0w >> 6;                // i is wave-uniform (p-range spans one i)
    const float* xb = x + (size_t)n * DD * PP;

    f32x4 acc[4][4];
#pragma unroll
    for (int a = 0; a < 4; ++a)
#pragma unroll
        for (int b = 0; b < 4; ++b) acc[a][b] = (f32x4)0.f;

#pragma unroll
    for (int kt = 0; kt < 4; ++kt) {
        int k0 = kt * 32 + q * 8;
        bf16x8 af[4];
#pragma unroll
        for (int st = 0; st < 4; ++st)
            af[st] = *(const bf16x8*)(c1t + (size_t)(s0w + st * 16 + c) * DD + k0);
#pragma unroll
        for (int pt = 0; pt < 4; ++pt) {
            const float* xp = xb + (size_t)k0 * PP + (p0w + pt * 16 + c);
            float f0 = xp[0 * PP], f1 = xp[1 * PP], f2 = xp[2 * PP], f3 = xp[3 * PP];
            float f4 = xp[4 * PP], f5 = xp[5 * PP], f6 = xp[6 * PP], f7 = xp[7 * PP];
            union { unsigned int u[4]; bf16x8 v; } bb;
            bb.u[0] = __builtin_amdgcn_perm(fbits(f1), fbits(f0), 0x07060302u);
            bb.u[1] = __builtin_amdgcn_perm(fbits(f3), fbits(f2), 0x07060302u);
            bb.u[2] = __builtin_amdgcn_perm(fbits(f5), fbits(f4), 0x07060302u);
            bb.u[3] = __builtin_amdgcn_perm(fbits(f7), fbits(f6), 0x07060302u);
#pragma unroll
            for (int st = 0; st < 4; ++st)
                acc[st][pt] = __builtin_amdgcn_mfma_f32_16x16x32_bf16(af[st], bb.v,
                                                                     acc[st][pt], 0, 0, 0);
        }
    }

    // epilogue: D[row][col]: row = s-local = q*4+reg, col = p-local = c
#pragma unroll
    for (int st = 0; st < 4; ++st) {
#pragma unroll
        for (int r = 0; r < 4; ++r) {
            int s = s0w + st * 16 + q * 4 + r;
            float uiv = us[s * USTR + iw];
            float* orow = out + ((size_t)(n * SS + s)) * PP;
#pragma unroll
            for (int pt = 0; pt < 4; ++pt) {
                int p = p0w + pt * 16 + c;
                int j = p & 63;
                orow[p] = acc[st][pt][r] + uiv + us[s * USTR + j];
            }
        }
    }
}

// ---------------------------------------------------------------------------
extern "C" void kernel_launch(void* const* d_in, const int* in_sizes, int n_in,
                              void* d_out, int out_size, void* d_ws, size_t ws_size,
                              hipStream_t stream) {
    const float* x      = (const float*)d_in[0];   // [N,D,M,M]
    const float* coeffs = (const float*)d_in[1];   // [D,S,5]
    const float* bias   = (const float*)d_in[2];   // [S]
    float* out = (float*)d_out;
    float* ws  = (float*)d_ws;

    float*          cpk = ws + OFF_CPK;
    unsigned short* c1t = (unsigned short*)(ws + OFF_C1T);
    float*          mc  = ws + OFF_MC;
    float*          dg  = ws + OFF_DG;
    float*          md  = ws + OFF_MD;
    float*          ma  = ws + OFF_MA;
    float*          up  = ws + OFF_UP;

    pack_k<<<DSZ / 256, 256, 0, stream>>>(coeffs, cpk, c1t);
    stats_k<<<NN * DD / 4, 256, 0, stream>>>(x, mc, dg, md, ma);
    combine_k<<<dim3(8, NN), 256, 0, stream>>>(cpk, mc, dg, md, ma, bias, up);
    gemm_k<<<dim3(PP / 128, NN), 256, 0, stream>>>(x, c1t, up, out);
}